// Round 4
// baseline (33.557 us; speedup 1.0000x reference)
//
#include <hip/hip_runtime.h>

// MeanPooling: xs [B=16, T=2048, D=1024] fp32, xs_len [B] (int64 or int32), out [B, D] fp32.
// out[b][d] = sum_{t < len_b} xs[b][t][d] / len_b
//
// Two-phase, no atomics, no memset, proportional load balancing, ARRAY-FREE
// partition math (rule #20: runtime-indexed private arrays spill to scratch).
// Both kernels recompute deterministically from xs_len:
//   total = sum(len_b); cnt_b = ceil(len_b * NB / total); pref = running sum.
// K1: block i -> (sample b, slot j) with pref_b <= i < pref_b+cnt_b;
//     sums rows [j*len_b/cnt_b, (j+1)*len_b/cnt_b) into ws[i][0:1024].
// K2: block (b, c) reduces slots [pref_b, pref_b+cnt_b) for D-chunk c,
//     scales by 1/len_b, writes out.

#define B_ 16
#define T_ 2048
#define D_ 1024
#define NB 1024          // target active blocks in K1

__device__ __forceinline__ int load_len(const void* p, bool is64, int k)
{
    long long len = is64 ? ((const long long*)p)[k]
                         : (long long)((const int*)p)[k];
    if (len < 1) len = 1;
    if (len > T_) len = T_;
    return (int)len;
}

__device__ __forceinline__ bool sniff64(const void* p)
{
    // int64 storage: element 0 read as i64 is in [1, T_]. int32 storage:
    // the i64 read = len0 | (len1 << 32) >= 2^32 since len1 >= 1.
    const long long v0 = ((const long long*)p)[0];
    return (v0 >= 1 && v0 <= (long long)T_);
}

__global__ __launch_bounds__(256) void mp_partial(
    const float* __restrict__ xs,
    const void* __restrict__ len_ptr,
    float* __restrict__ ws)
{
    const int bid = blockIdx.x;
    const bool is64 = sniff64(len_ptr);

    unsigned total = 0;
    #pragma unroll
    for (int k = 0; k < B_; ++k) total += (unsigned)load_len(len_ptr, is64, k);

    // Array-free prefix scan + select: everything stays in registers.
    int b = -1, j = 0, len = 1, cb = 1;
    unsigned p = 0;
    #pragma unroll
    for (int k = 0; k < B_; ++k) {
        const int lk = load_len(len_ptr, is64, k);
        const int ck = (int)(((unsigned)lk * NB + total - 1u) / total);  // >= 1
        const bool hit = (b < 0) && ((unsigned)bid < p + (unsigned)ck);
        if (hit) { b = k; j = bid - (int)p; len = lk; cb = ck; }
        p += (unsigned)ck;
    }
    if (b < 0) return;   // bid beyond total assigned blocks

    // products <= 2048 * 1024 < 2^21 -> cheap u32 division
    const int r0 = (int)(((unsigned)j * (unsigned)len) / (unsigned)cb);
    const int r1 = (int)(((unsigned)(j + 1) * (unsigned)len) / (unsigned)cb);

    const int tid = threadIdx.x;     // 256 threads x float4 = full 1024-wide D row

    const float4* src = (const float4*)xs + ((long)b * T_ + r0) * (D_ / 4) + tid;
    float4 acc = make_float4(0.f, 0.f, 0.f, 0.f);

    #pragma unroll 4
    for (int t = r0; t < r1; ++t) {
        float4 v = *src;
        src += (D_ / 4);
        acc.x += v.x; acc.y += v.y; acc.z += v.z; acc.w += v.w;
    }

    ((float4*)ws)[(long)bid * (D_ / 4) + tid] = acc;
}

__global__ __launch_bounds__(256) void mp_reduce(
    const float* __restrict__ ws,
    const void* __restrict__ len_ptr,
    float* __restrict__ out)
{
    const int b = blockIdx.x >> 2;   // 4 blocks per sample
    const int c = blockIdx.x & 3;    // D-chunk: 256 floats = 64 float4
    const int lane = threadIdx.x & 63;
    const int w = threadIdx.x >> 6;  // 4 waves stride the slots

    const bool is64 = sniff64(len_ptr);

    unsigned total = 0;
    #pragma unroll
    for (int k = 0; k < B_; ++k) total += (unsigned)load_len(len_ptr, is64, k);

    int s0 = 0, cb = 1, len = 1;
    unsigned p = 0;
    #pragma unroll
    for (int k = 0; k < B_; ++k) {
        const int lk = load_len(len_ptr, is64, k);
        const int ck = (int)(((unsigned)lk * NB + total - 1u) / total);
        if (k == b) { s0 = (int)p; cb = ck; len = lk; }
        p += (unsigned)ck;
    }

    const int d4 = c * 64 + lane;    // float4 index in [0, 256)
    const float4* wsp = (const float4*)ws;

    float4 acc = make_float4(0.f, 0.f, 0.f, 0.f);
    for (int s = s0 + w; s < s0 + cb; s += 4) {
        float4 v = wsp[(long)s * (D_ / 4) + d4];
        acc.x += v.x; acc.y += v.y; acc.z += v.z; acc.w += v.w;
    }

    __shared__ float4 sm[4][64];
    sm[w][lane] = acc;
    __syncthreads();

    if (w == 0) {
        float4 a0 = sm[0][lane], a1 = sm[1][lane], a2 = sm[2][lane], a3 = sm[3][lane];
        const float inv = 1.0f / (float)len;
        float4 r;
        r.x = (a0.x + a1.x + a2.x + a3.x) * inv;
        r.y = (a0.y + a1.y + a2.y + a3.y) * inv;
        r.z = (a0.z + a1.z + a2.z + a3.z) * inv;
        r.w = (a0.w + a1.w + a2.w + a3.w) * inv;
        ((float4*)out)[(long)b * (D_ / 4) + d4] = r;
    }
}

extern "C" void kernel_launch(void* const* d_in, const int* in_sizes, int n_in,
                              void* d_out, int out_size, void* d_ws, size_t ws_size,
                              hipStream_t stream)
{
    const float* xs = (const float*)d_in[0];
    const void* xs_len = d_in[1];
    float* out = (float*)d_out;
    float* ws = (float*)d_ws;    // uses up to (NB + B_) * D_ * 4 B ~= 4.06 MiB

    mp_partial<<<dim3(NB + B_), dim3(256), 0, stream>>>(xs, xs_len, ws);
    mp_reduce<<<dim3(B_ * 4), dim3(256), 0, stream>>>(ws, xs_len, out);
}